// Round 1
// 305.489 us; speedup vs baseline: 1.0874x; 1.0874x over previous
//
#include <hip/hip_runtime.h>
#include <hip/hip_bf16.h>
#include <math.h>

#define N_NODES 200000
#define EMB_DIM 64
#define E_ADJ 1600000
#define E_TR 65536
#define NUM_NEG 16
#define EPS 1e-7f
#define MIN_NORM 1e-15f
#define MAX_SQDIST 50.0f
#define MARGIN 0.1f
#define LOSS_BLOCKS (E_TR / 4)     // 16384 blocks, 4 edges (waves) each
#define SPMM_BLOCKS 2048           // persistent: 8 blocks/CU x 256 CU; blocks >=2000 exit whole
#define NWAVES (SPMM_BLOCKS * 4)   // 8192 waves
#define RPW 25                     // rows per wave (contiguous block; 100 rows/block -> uniform exit)
#define LDS_CAP 512                // staged edges per wave (~200 expected)

#define PACK_BLOCKS ((E_ADJ + 255) / 256)        // 6250
#define RP_BLOCKS   ((N_NODES + 1 + 255) / 256)  // 782
#define LOG_BLOCKS  ((N_NODES + 15) / 16)        // 12500

typedef float f4 __attribute__((ext_vector_type(4)));

__device__ __forceinline__ float group_reduce16(float v) {
    v += __shfl_xor(v, 8, 64);
    v += __shfl_xor(v, 4, 64);
    v += __shfl_xor(v, 2, 64);
    v += __shfl_xor(v, 1, 64);
    return v;
}

__device__ __forceinline__ float group_reduce8(float v) {
    v += __shfl_xor(v, 4, 64);
    v += __shfl_xor(v, 2, 64);
    v += __shfl_xor(v, 1, 64);
    return v;
}

__device__ __forceinline__ float dot4(f4 a, f4 b) {
    return a.x * b.x + a.y * b.y + a.z * b.z + a.w * b.w;
}

// ---- bf16 pack/unpack (RNE, unbiased) ----
__device__ __forceinline__ unsigned bfr(float f) {
    unsigned u = __float_as_uint(f);
    return (u + 0x7fffu + ((u >> 16) & 1u)) >> 16;
}
__device__ __forceinline__ uint2 f42bf(f4 v) {
    return make_uint2(bfr(v.x) | (bfr(v.y) << 16), bfr(v.z) | (bfr(v.w) << 16));
}
__device__ __forceinline__ f4 bf2f4(uint2 g) {
    f4 r;
    r.x = __uint_as_float(g.x << 16);
    r.y = __uint_as_float(g.x & 0xffff0000u);
    r.z = __uint_as_float(g.y << 16);
    r.w = __uint_as_float(g.y & 0xffff0000u);
    return r;
}

// 8 bf16 dims (one uint4) * scalar val, fp32 accumulate. Per-dim fmac order
// identical to the 16-lane/dwordx2 version (sequential over edge index k).
__device__ __forceinline__ void fma8(f4& a0, f4& a1, uint4 g, float v) {
    f4 lo, hi;
    lo.x = __uint_as_float(g.x << 16);
    lo.y = __uint_as_float(g.x & 0xffff0000u);
    lo.z = __uint_as_float(g.y << 16);
    lo.w = __uint_as_float(g.y & 0xffff0000u);
    hi.x = __uint_as_float(g.z << 16);
    hi.y = __uint_as_float(g.z & 0xffff0000u);
    hi.z = __uint_as_float(g.w << 16);
    hi.w = __uint_as_float(g.w & 0xffff0000u);
    a0 += lo * v;
    a1 += hi * v;
}

// Prelude: pack edges + row_ptr + logmap0, one dispatch (block-range split).
__global__ void prelude_kernel(const int* __restrict__ cols, const float* __restrict__ vals,
                               int2* __restrict__ ev, const int* __restrict__ rows,
                               int* __restrict__ rp, const float* __restrict__ w,
                               uint2* __restrict__ xt) {
    int b = blockIdx.x;
    if (b < PACK_BLOCKS) {
        int i = b * 256 + threadIdx.x;
        if (i < E_ADJ) ev[i] = make_int2(cols[i] << 3, __float_as_int(vals[i]));  // uint4-unit index
    } else if (b < PACK_BLOCKS + RP_BLOCKS) {
        int r = (b - PACK_BLOCKS) * 256 + threadIdx.x;
        if (r <= N_NODES) {
            int lo = 0, hi = E_ADJ;
            while (lo < hi) {
                int mid = (lo + hi) >> 1;
                if (rows[mid] < r) lo = mid + 1; else hi = mid;
            }
            rp[r] = lo;
        }
    } else {
        int bb = b - PACK_BLOCKS - RP_BLOCKS;
        int wave = bb * 4 + (threadIdx.x >> 6);
        int lane = threadIdx.x & 63;
        int e = lane >> 4, d = lane & 15;
        int node = wave * 4 + e;
        if (node < N_NODES) {
            f4 v = ((const f4*)w)[(node << 4) + d];
            f4 y = v;
            if (d == 0) y.x = 0.0f;
            float n2 = group_reduce16(dot4(y, y));
            float ynorm = fmaxf(sqrtf(n2), MIN_NORM);
            float w0 = __shfl(v.x, lane & 48, 64);
            float theta = fmaxf(w0, 1.0f + EPS);
            float scale = acoshf(theta) / ynorm;
            xt[(node << 4) + d] = f42bf(y * scale);
        }
    }
}

// Hot path: all of the group's edges are staged in LDS (wave-uniform check).
// s,e are relative to ebase. 8-lane group owns the full 64-dim row.
__device__ __forceinline__ void row_accum_lds(f4& a0, f4& a1,
                                              const uint4* __restrict__ h_in,
                                              const int2* L, int s, int e, int d) {
    int k = s;
    for (; k + 2 <= e; k += 2) {
        int2 cv0 = L[k];
        int2 cv1 = L[k + 1];
        uint4 g0 = h_in[cv0.x + d];
        uint4 g1 = h_in[cv1.x + d];
        fma8(a0, a1, g0, __int_as_float(cv0.y));
        fma8(a0, a1, g1, __int_as_float(cv1.y));
    }
    if (k < e) {
        int2 cv = L[k];
        fma8(a0, a1, h_in[cv.x + d], __int_as_float(cv.y));
    }
}

// Rare fallback (wave has > LDS_CAP edges): read ev straight from global (L2).
__device__ __forceinline__ void row_accum_glb(f4& a0, f4& a1,
                                              const uint4* __restrict__ h_in,
                                              const int2* __restrict__ ev,
                                              int s, int e, int d) {
    int k = s;
    for (; k + 2 <= e; k += 2) {
        int2 cv0 = ev[k];
        int2 cv1 = ev[k + 1];
        uint4 g0 = h_in[cv0.x + d];
        uint4 g1 = h_in[cv1.x + d];
        fma8(a0, a1, g0, __int_as_float(cv0.y));
        fma8(a0, a1, g1, __int_as_float(cv1.y));
    }
    if (k < e) {
        int2 cv = ev[k];
        fma8(a0, a1, h_in[cv.x + d], __int_as_float(cv.y));
    }
}

// Kernel: persistent SpMM layer. Wave owns RPW contiguous rows; each 8-lane
// group processes one row (8 rows in flight), dwordx4 gathers (128B/row).
__global__ __launch_bounds__(256) void spmm_kernel(const uint4* __restrict__ h_in,
                                                   uint4* __restrict__ h_out,
                                                   const int2* __restrict__ ev,
                                                   const int* __restrict__ rp) {
    __shared__ int2 evs[4][LDS_CAP];               // 16 KB/block
    int wib = threadIdx.x >> 6;
    int lane = threadIdx.x & 63;
    int g = lane >> 3, d = lane & 7;
    int wid = __builtin_amdgcn_readfirstlane(blockIdx.x * 4 + wib);
    int r0 = wid * RPW;
    if (r0 >= N_NODES) return;                     // block-uniform (100 rows/block)
    int r1 = min(r0 + RPW, N_NODES);
    int ebase = rp[r0];                            // s_load
    int etot  = rp[r1];
    int nst   = etot - ebase;
    bool allst = nst <= LDS_CAP;                   // wave-uniform; ~always true
    int staged = min(nst, LDS_CAP);
    int2* L = evs[wib];
    for (int k = lane; k < staged; k += 64)        // coalesced bulk stage
        L[k] = ev[ebase + k];
    __syncthreads();

    for (int base = r0; base < r1; base += 8) {
        int row = base + g;
        bool valid = row < r1;
        int s = 0, e = 0;
        if (valid) { s = rp[row]; e = rp[row + 1]; }
        f4 a0 = {0.f, 0.f, 0.f, 0.f}, a1 = {0.f, 0.f, 0.f, 0.f};
        if (allst) row_accum_lds(a0, a1, h_in, L, s - ebase, e - ebase, d);
        else       row_accum_glb(a0, a1, h_in, ev, s, e, d);
        if (valid) {
            uint2 p0 = f42bf(a0), p1 = f42bf(a1);
            h_out[(row << 3) + d] = make_uint4(p0.x, p0.y, p1.x, p1.y);  // 1 KB contiguous/wave
        }
    }
}

// Kernel: persistent fused layer-3 SpMM + (h1+h2+h3) + expmap0 + proj.
__global__ __launch_bounds__(256) void spmm_expmap_kernel(const uint4* __restrict__ h_gather,
                                                          const uint4* __restrict__ h1,
                                                          const uint4* __restrict__ h2,
                                                          float* __restrict__ h,
                                                          float* __restrict__ nrm2,
                                                          const int2* __restrict__ ev,
                                                          const int* __restrict__ rp) {
    __shared__ int2 evs[4][LDS_CAP];
    int wib = threadIdx.x >> 6;
    int lane = threadIdx.x & 63;
    int g = lane >> 3, d = lane & 7;
    int wid = __builtin_amdgcn_readfirstlane(blockIdx.x * 4 + wib);
    int r0 = wid * RPW;
    if (r0 >= N_NODES) return;
    int r1 = min(r0 + RPW, N_NODES);
    int ebase = rp[r0];
    int etot  = rp[r1];
    int nst   = etot - ebase;
    bool allst = nst <= LDS_CAP;
    int staged = min(nst, LDS_CAP);
    int2* L = evs[wib];
    for (int k = lane; k < staged; k += 64)
        L[k] = ev[ebase + k];
    __syncthreads();

    for (int base = r0; base < r1; base += 8) {
        int row = base + g;
        bool valid = row < r1;
        int s = 0, e = 0;
        uint4 b1 = make_uint4(0, 0, 0, 0), b2 = make_uint4(0, 0, 0, 0);
        if (valid) {
            s = rp[row]; e = rp[row + 1];
            b1 = h1[(row << 3) + d];               // issue early, overlap gathers
            b2 = h2[(row << 3) + d];
        }
        f4 a0 = {0.f, 0.f, 0.f, 0.f}, a1 = {0.f, 0.f, 0.f, 0.f};
        if (allst) row_accum_lds(a0, a1, h_gather, L, s - ebase, e - ebase, d);
        else       row_accum_glb(a0, a1, h_gather, ev, s, e, d);
        if (valid) {
            f4 h1lo = bf2f4(make_uint2(b1.x, b1.y)), h1hi = bf2f4(make_uint2(b1.z, b1.w));
            f4 h2lo = bf2f4(make_uint2(b2.x, b2.y)), h2hi = bf2f4(make_uint2(b2.z, b2.w));
            f4 u0 = (h1lo + h2lo) + a0;            // match ref accumulate order
            f4 u1 = (h1hi + h2hi) + a1;
            f4 x0 = u0, x1 = u1;
            if (d == 0) x0.x = 0.0f;
            float n2 = group_reduce8(dot4(x0, x0) + dot4(x1, x1));
            float xn = fmaxf(sqrtf(n2), MIN_NORM);
            float sh = sinhf(xn);
            float sc = sh / xn;
            f4 rv0 = x0 * sc, rv1 = x1 * sc;
            float rr2 = group_reduce8(dot4(rv0, rv0) + dot4(rv1, rv1));
            float first = sqrtf(1.0f + rr2);
            f4 o0 = rv0, o1 = rv1;
            if (d == 0) o0.x = first;
            ((f4*)h)[(row << 4) + 2 * d]     = o0;  // 256 B contiguous per group-row
            ((f4*)h)[(row << 4) + 2 * d + 1] = o1;
            if (d == 0) nrm2[row] = first * first + rr2;
        }
    }
}

// Kernel: triplet loss + hard-negative mining. One wave per edge; lane=16e+d.
__global__ void loss_kernel(const float* __restrict__ h, const float* __restrict__ nrm2,
                            const int* __restrict__ anchor, const int* __restrict__ pos,
                            const int* __restrict__ neg, float* __restrict__ partials) {
    int wib = threadIdx.x >> 6;
    int lane = threadIdx.x & 63;
    int e = lane >> 4, d = lane & 15;
    int i = __builtin_amdgcn_readfirstlane(blockIdx.x * 4 + wib);
    const f4* H = (const f4*)h;

    int ia = anchor[i], ip = pos[i];               // s_load
    f4 a4 = H[(ia << 4) + d];
    f4 p4 = H[(ip << 4) + d];
    int4 nb4 = ((const int4*)(neg + (size_t)i * NUM_NEG))[e];  // group e: j = 4e+b

    float s[4];
    s[0] = dot4(p4, H[(nb4.x << 4) + d]);
    s[1] = dot4(p4, H[(nb4.y << 4) + d]);
    s[2] = dot4(p4, H[(nb4.z << 4) + d]);
    s[3] = dot4(p4, H[(nb4.w << 4) + d]);
    float dap = dot4(a4, p4);

    // reduce-scatter the 4 values across the 16-lane group
    {
        bool hi = (d & 8) != 0;
        float send0 = hi ? s[0] : s[2];
        float send1 = hi ? s[1] : s[3];
        float r0 = __shfl_xor(send0, 8, 64);
        float r1 = __shfl_xor(send1, 8, 64);
        float k0 = hi ? s[2] : s[0];
        float k1 = hi ? s[3] : s[1];
        s[0] = k0 + r0;
        s[1] = k1 + r1;
    }
    float sv;
    {
        bool hi = (d & 4) != 0;
        float send = hi ? s[0] : s[1];
        float r = __shfl_xor(send, 4, 64);
        float k = hi ? s[1] : s[0];
        sv = k + r;
    }
    sv += __shfl_xor(sv, 2, 64);
    sv += __shfl_xor(sv, 1, 64);
    // lane (e,d) holds <p,n_j> for j = 4e + b, b = ((d>>3)&1)*2 + ((d>>2)&1)
    int b_lane = ((d >> 3) & 1) * 2 + ((d >> 2) & 1);
    int nidx_lane = (d & 8) ? ((d & 4) ? nb4.w : nb4.z)
                            : ((d & 4) ? nb4.y : nb4.x);
    int j_lane = 4 * e + b_lane;

    float np2 = nrm2[ip];
    float bd = nrm2[nidx_lane] + np2 - 2.0f * sv;
    int bj = j_lane;
    // wave-wide argmin, first-occurrence tie-break (ties are duplicate nodes ->
    // bitwise-identical d2, so smaller-j rule matches jnp.argmin exactly)
    #pragma unroll
    for (int off = 32; off > 0; off >>= 1) {
        float od = __shfl_xor(bd, off, 64);
        int   oj = __shfl_xor(bj, off, 64);
        if (od < bd || (od == bd && oj < bj)) { bd = od; bj = oj; }
    }
    int bn = neg[(size_t)i * NUM_NEG + __builtin_amdgcn_readfirstlane(bj)];  // s_load
    f4 w4 = H[(bn << 4) + d];
    float dan = group_reduce16(dot4(a4, w4));
    dap = group_reduce16(dap);

    float loss = 0.0f;
    if (lane == 0) {
        float a0 = a4.x, p0 = p4.x, n0 = w4.x;
        float mink = dap - 2.0f * a0 * p0;
        float th = fmaxf(-mink, 1.0f + EPS);
        float ac = acoshf(th);
        float pos_score = fminf(ac * ac, MAX_SQDIST);
        float score = (1.0f - mink - a0 - p0) / (a0 * p0);
        float wgt = 1.0f / (1.0f + expf(score));        // sigmoid(-score)
        float minkn = dan - 2.0f * a0 * n0;
        float thn = fmaxf(-minkn, 1.0f + EPS);
        float acn = acoshf(thn);
        float neg_score = fminf(acn * acn, MAX_SQDIST);
        loss = fmaxf(pos_score - neg_score + MARGIN * wgt, 0.0f);
    }
    __shared__ float part[4];
    if (lane == 0) part[wib] = loss;
    __syncthreads();
    if (threadIdx.x == 0)
        partials[blockIdx.x] = part[0] + part[1] + part[2] + part[3];
}

// Final reduce. Single block, 1024 threads.
__global__ void reduce_kernel(const float* __restrict__ partials, float* __restrict__ out) {
    int tid = threadIdx.x;
    float s = 0.0f;
    for (int i = tid; i < LOSS_BLOCKS; i += 1024)
        s += partials[i];
    #pragma unroll
    for (int off = 32; off > 0; off >>= 1)
        s += __shfl_xor(s, off, 64);
    __shared__ float part[16];
    if ((tid & 63) == 0) part[tid >> 6] = s;
    __syncthreads();
    if (tid == 0) {
        float t = 0.0f;
        #pragma unroll
        for (int k = 0; k < 16; ++k) t += part[k];
        out[0] = t;
    }
}

extern "C" void kernel_launch(void* const* d_in, const int* in_sizes, int n_in,
                              void* d_out, int out_size, void* d_ws, size_t ws_size,
                              hipStream_t stream) {
    const float* weight   = (const float*)d_in[0];
    const float* adj_vals = (const float*)d_in[1];
    const int*   adj_row  = (const int*)d_in[2];
    const int*   adj_col  = (const int*)d_in[3];
    const int*   anchor   = (const int*)d_in[4];
    const int*   pos      = (const int*)d_in[5];
    const int*   neg      = (const int*)d_in[6];
    float* out = (float*)d_out;

    const size_t NODEF32 = (size_t)N_NODES * EMB_DIM * sizeof(float);           // 51.2 MB
    const size_t NODEBF  = (size_t)N_NODES * EMB_DIM * sizeof(unsigned short);  // 25.6 MB
    const size_t MB = 1024 * 1024;
    char* ws = (char*)d_ws;
    float* hfin = (float*)(ws);                        // final h (fp32)
    uint2* bf0  = (uint2*)(ws + NODEF32);              // x_t bf16
    char*  bf1  = (char*) (ws + NODEF32 + NODEBF);     // h1 bf16
    char*  bf2  = (char*) (ws + NODEF32 + 2 * NODEBF); // h2 bf16
    int*   rp   = (int*)  (ws + NODEF32 + 3 * NODEBF);            // row_ptr (800 KB)
    float* nrm2 = (float*)(ws + NODEF32 + 3 * NODEBF + 1 * MB);   // ||h||^2 (800 KB)
    int2*  ev   = (int2*) (ws + NODEF32 + 3 * NODEBF + 2 * MB);   // packed edges (12.8 MB)
    float* partials = (float*)(ws + NODEF32 + 3 * NODEBF + 16 * MB); // 64 KB

    prelude_kernel<<<PACK_BLOCKS + RP_BLOCKS + LOG_BLOCKS, 256, 0, stream>>>(
        adj_col, adj_vals, ev, adj_row, rp, weight, bf0);
    spmm_kernel<<<SPMM_BLOCKS, 256, 0, stream>>>((const uint4*)bf0, (uint4*)bf1, ev, rp);
    spmm_kernel<<<SPMM_BLOCKS, 256, 0, stream>>>((const uint4*)bf1, (uint4*)bf2, ev, rp);
    spmm_expmap_kernel<<<SPMM_BLOCKS, 256, 0, stream>>>((const uint4*)bf2, (const uint4*)bf1,
                                                        (const uint4*)bf2, hfin, nrm2, ev, rp);
    loss_kernel<<<LOSS_BLOCKS, 256, 0, stream>>>(hfin, nrm2, anchor, pos, neg, partials);
    reduce_kernel<<<1, 1024, 0, stream>>>(partials, out);
}

// Round 2
// 294.552 us; speedup vs baseline: 1.1277x; 1.0371x over previous
//
#include <hip/hip_runtime.h>
#include <hip/hip_bf16.h>
#include <math.h>

#define N_NODES 200000
#define EMB_DIM 64
#define E_ADJ 1600000
#define E_TR 65536
#define NUM_NEG 16
#define EPS 1e-7f
#define MIN_NORM 1e-15f
#define MAX_SQDIST 50.0f
#define MARGIN 0.1f
#define EPW 8                       // edges per wave in loss kernel
#define LOSS_BLOCKS (E_TR / (4 * EPW))   // 2048 blocks, 4 waves x 8 edges each
#define NPART (E_TR / 4)            // 16384 partials (same granularity/order as before)
#define SPMM_BLOCKS 2048           // persistent: 8 blocks/CU x 256 CU
#define NWAVES (SPMM_BLOCKS * 4)   // 8192 waves
#define RPW 25                     // rows per wave (contiguous block)
#define LDS_CAP 512                // staged edges per wave (~200 expected)

#define PACK_BLOCKS ((E_ADJ + 255) / 256)        // 6250
#define RP_BLOCKS   ((N_NODES + 1 + 255) / 256)  // 782
#define LOG_BLOCKS  ((N_NODES + 15) / 16)        // 12500

typedef float f4 __attribute__((ext_vector_type(4)));

__device__ __forceinline__ float group_reduce16(float v) {
    v += __shfl_xor(v, 8, 64);
    v += __shfl_xor(v, 4, 64);
    v += __shfl_xor(v, 2, 64);
    v += __shfl_xor(v, 1, 64);
    return v;
}

__device__ __forceinline__ float group_reduce8(float v) {
    v += __shfl_xor(v, 4, 64);
    v += __shfl_xor(v, 2, 64);
    v += __shfl_xor(v, 1, 64);
    return v;
}

__device__ __forceinline__ float dot4(f4 a, f4 b) {
    return a.x * b.x + a.y * b.y + a.z * b.z + a.w * b.w;
}

// ---- bf16 pack/unpack (RNE, unbiased) ----
__device__ __forceinline__ unsigned bfr(float f) {
    unsigned u = __float_as_uint(f);
    return (u + 0x7fffu + ((u >> 16) & 1u)) >> 16;
}
__device__ __forceinline__ uint2 f42bf(f4 v) {
    return make_uint2(bfr(v.x) | (bfr(v.y) << 16), bfr(v.z) | (bfr(v.w) << 16));
}
__device__ __forceinline__ f4 bf2f4(uint2 g) {
    f4 r;
    r.x = __uint_as_float(g.x << 16);
    r.y = __uint_as_float(g.x & 0xffff0000u);
    r.z = __uint_as_float(g.y << 16);
    r.w = __uint_as_float(g.y & 0xffff0000u);
    return r;
}

// 8 bf16 dims (one uint4) * scalar val, fp32 accumulate.
__device__ __forceinline__ void fma8(f4& a0, f4& a1, uint4 g, float v) {
    f4 lo, hi;
    lo.x = __uint_as_float(g.x << 16);
    lo.y = __uint_as_float(g.x & 0xffff0000u);
    lo.z = __uint_as_float(g.y << 16);
    lo.w = __uint_as_float(g.y & 0xffff0000u);
    hi.x = __uint_as_float(g.z << 16);
    hi.y = __uint_as_float(g.z & 0xffff0000u);
    hi.z = __uint_as_float(g.w << 16);
    hi.w = __uint_as_float(g.w & 0xffff0000u);
    a0 += lo * v;
    a1 += hi * v;
}

// Prelude: pack edges + row_ptr + logmap0, one dispatch (block-range split).
__global__ void prelude_kernel(const int* __restrict__ cols, const float* __restrict__ vals,
                               int2* __restrict__ ev, const int* __restrict__ rows,
                               int* __restrict__ rp, const float* __restrict__ w,
                               uint2* __restrict__ xt) {
    int b = blockIdx.x;
    if (b < PACK_BLOCKS) {
        int i = b * 256 + threadIdx.x;
        if (i < E_ADJ) ev[i] = make_int2(cols[i] << 3, __float_as_int(vals[i]));  // uint4-unit index
    } else if (b < PACK_BLOCKS + RP_BLOCKS) {
        int r = (b - PACK_BLOCKS) * 256 + threadIdx.x;
        if (r <= N_NODES) {
            int lo = 0, hi = E_ADJ;
            while (lo < hi) {
                int mid = (lo + hi) >> 1;
                if (rows[mid] < r) lo = mid + 1; else hi = mid;
            }
            rp[r] = lo;
        }
    } else {
        int bb = b - PACK_BLOCKS - RP_BLOCKS;
        int wave = bb * 4 + (threadIdx.x >> 6);
        int lane = threadIdx.x & 63;
        int e = lane >> 4, d = lane & 15;
        int node = wave * 4 + e;
        if (node < N_NODES) {
            f4 v = ((const f4*)w)[(node << 4) + d];
            f4 y = v;
            if (d == 0) y.x = 0.0f;
            float n2 = group_reduce16(dot4(y, y));
            float ynorm = fmaxf(sqrtf(n2), MIN_NORM);
            float w0 = __shfl(v.x, lane & 48, 64);
            float theta = fmaxf(w0, 1.0f + EPS);
            float scale = acoshf(theta) / ynorm;
            xt[(node << 4) + d] = f42bf(y * scale);
        }
    }
}

// Hot path: all of the group's edges are staged in LDS (wave-uniform check).
__device__ __forceinline__ void row_accum_lds(f4& a0, f4& a1,
                                              const uint4* __restrict__ h_in,
                                              const int2* L, int s, int e, int d) {
    int k = s;
    for (; k + 2 <= e; k += 2) {
        int2 cv0 = L[k];
        int2 cv1 = L[k + 1];
        uint4 g0 = h_in[cv0.x + d];
        uint4 g1 = h_in[cv1.x + d];
        fma8(a0, a1, g0, __int_as_float(cv0.y));
        fma8(a0, a1, g1, __int_as_float(cv1.y));
    }
    if (k < e) {
        int2 cv = L[k];
        fma8(a0, a1, h_in[cv.x + d], __int_as_float(cv.y));
    }
}

// Rare fallback (wave has > LDS_CAP edges): read ev straight from global (L2).
__device__ __forceinline__ void row_accum_glb(f4& a0, f4& a1,
                                              const uint4* __restrict__ h_in,
                                              const int2* __restrict__ ev,
                                              int s, int e, int d) {
    int k = s;
    for (; k + 2 <= e; k += 2) {
        int2 cv0 = ev[k];
        int2 cv1 = ev[k + 1];
        uint4 g0 = h_in[cv0.x + d];
        uint4 g1 = h_in[cv1.x + d];
        fma8(a0, a1, g0, __int_as_float(cv0.y));
        fma8(a0, a1, g1, __int_as_float(cv1.y));
    }
    if (k < e) {
        int2 cv = ev[k];
        fma8(a0, a1, h_in[cv.x + d], __int_as_float(cv.y));
    }
}

// Kernel: persistent SpMM layer. Wave owns RPW contiguous rows; each 8-lane
// group processes one row (8 rows in flight), dwordx4 gathers (128B/row).
__global__ __launch_bounds__(256) void spmm_kernel(const uint4* __restrict__ h_in,
                                                   uint4* __restrict__ h_out,
                                                   const int2* __restrict__ ev,
                                                   const int* __restrict__ rp) {
    __shared__ int2 evs[4][LDS_CAP];               // 16 KB/block
    int wib = threadIdx.x >> 6;
    int lane = threadIdx.x & 63;
    int g = lane >> 3, d = lane & 7;
    int wid = __builtin_amdgcn_readfirstlane(blockIdx.x * 4 + wib);
    int r0 = wid * RPW;
    if (r0 >= N_NODES) return;                     // block-uniform (100 rows/block)
    int r1 = min(r0 + RPW, N_NODES);
    int ebase = rp[r0];                            // s_load
    int etot  = rp[r1];
    int nst   = etot - ebase;
    bool allst = nst <= LDS_CAP;                   // wave-uniform; ~always true
    int staged = min(nst, LDS_CAP);
    int2* L = evs[wib];
    for (int k = lane; k < staged; k += 64)        // coalesced bulk stage
        L[k] = ev[ebase + k];
    __syncthreads();

    for (int base = r0; base < r1; base += 8) {
        int row = base + g;
        bool valid = row < r1;
        int s = 0, e = 0;
        if (valid) { s = rp[row]; e = rp[row + 1]; }
        f4 a0 = {0.f, 0.f, 0.f, 0.f}, a1 = {0.f, 0.f, 0.f, 0.f};
        if (allst) row_accum_lds(a0, a1, h_in, L, s - ebase, e - ebase, d);
        else       row_accum_glb(a0, a1, h_in, ev, s, e, d);
        if (valid) {
            uint2 p0 = f42bf(a0), p1 = f42bf(a1);
            h_out[(row << 3) + d] = make_uint4(p0.x, p0.y, p1.x, p1.y);  // 1 KB contiguous/wave
        }
    }
}

// Kernel: persistent fused layer-3 SpMM + (h1+h2+h3) + expmap0 + proj.
__global__ __launch_bounds__(256) void spmm_expmap_kernel(const uint4* __restrict__ h_gather,
                                                          const uint4* __restrict__ h1,
                                                          const uint4* __restrict__ h2,
                                                          float* __restrict__ h,
                                                          float* __restrict__ nrm2,
                                                          const int2* __restrict__ ev,
                                                          const int* __restrict__ rp) {
    __shared__ int2 evs[4][LDS_CAP];
    int wib = threadIdx.x >> 6;
    int lane = threadIdx.x & 63;
    int g = lane >> 3, d = lane & 7;
    int wid = __builtin_amdgcn_readfirstlane(blockIdx.x * 4 + wib);
    int r0 = wid * RPW;
    if (r0 >= N_NODES) return;
    int r1 = min(r0 + RPW, N_NODES);
    int ebase = rp[r0];
    int etot  = rp[r1];
    int nst   = etot - ebase;
    bool allst = nst <= LDS_CAP;
    int staged = min(nst, LDS_CAP);
    int2* L = evs[wib];
    for (int k = lane; k < staged; k += 64)
        L[k] = ev[ebase + k];
    __syncthreads();

    for (int base = r0; base < r1; base += 8) {
        int row = base + g;
        bool valid = row < r1;
        int s = 0, e = 0;
        uint4 b1 = make_uint4(0, 0, 0, 0), b2 = make_uint4(0, 0, 0, 0);
        if (valid) {
            s = rp[row]; e = rp[row + 1];
            b1 = h1[(row << 3) + d];               // issue early, overlap gathers
            b2 = h2[(row << 3) + d];
        }
        f4 a0 = {0.f, 0.f, 0.f, 0.f}, a1 = {0.f, 0.f, 0.f, 0.f};
        if (allst) row_accum_lds(a0, a1, h_gather, L, s - ebase, e - ebase, d);
        else       row_accum_glb(a0, a1, h_gather, ev, s, e, d);
        if (valid) {
            f4 h1lo = bf2f4(make_uint2(b1.x, b1.y)), h1hi = bf2f4(make_uint2(b1.z, b1.w));
            f4 h2lo = bf2f4(make_uint2(b2.x, b2.y)), h2hi = bf2f4(make_uint2(b2.z, b2.w));
            f4 u0 = (h1lo + h2lo) + a0;            // match ref accumulate order
            f4 u1 = (h1hi + h2hi) + a1;
            f4 x0 = u0, x1 = u1;
            if (d == 0) x0.x = 0.0f;
            float n2 = group_reduce8(dot4(x0, x0) + dot4(x1, x1));
            float xn = fmaxf(sqrtf(n2), MIN_NORM);
            float sh = sinhf(xn);
            float sc = sh / xn;
            f4 rv0 = x0 * sc, rv1 = x1 * sc;
            float rr2 = group_reduce8(dot4(rv0, rv0) + dot4(rv1, rv1));
            float first = sqrtf(1.0f + rr2);
            f4 o0 = rv0, o1 = rv1;
            if (d == 0) o0.x = first;
            ((f4*)h)[(row << 4) + 2 * d]     = o0;  // 256 B contiguous per group-row
            ((f4*)h)[(row << 4) + 2 * d + 1] = o1;
            if (d == 0) nrm2[row] = first * first + rr2;
        }
    }
}

// Kernel: triplet loss + hard-negative mining. EPW edges per wave, pipelined;
// transcendental tail deferred and vectorized across lanes 0..EPW-1.
__global__ __launch_bounds__(256) void loss_kernel(const float* __restrict__ h, const float* __restrict__ nrm2,
                            const int* __restrict__ anchor, const int* __restrict__ pos,
                            const int* __restrict__ neg, float* __restrict__ partials) {
    int wib = threadIdx.x >> 6;
    int lane = threadIdx.x & 63;
    int e = lane >> 4, d = lane & 15;
    int w = __builtin_amdgcn_readfirstlane(blockIdx.x * 4 + wib);
    const f4* H = (const f4*)h;
    int i0 = w * EPW;

    // per-edge stashed scalars (lane t holds edge t's values); safe inits
    float fdap = 0.0f, fdan = 0.0f, fa0 = 1.0f, fp0 = 1.0f, fn0 = 1.0f;

    #pragma unroll 2
    for (int t = 0; t < EPW; ++t) {
        int i = i0 + t;
        int ia = anchor[i], ip = pos[i];               // s_load (wave-uniform i)
        f4 a4 = H[(ia << 4) + d];
        f4 p4 = H[(ip << 4) + d];
        int4 nb4 = ((const int4*)(neg + (size_t)i * NUM_NEG))[e];  // group e: j = 4e+b

        float s[4];
        s[0] = dot4(p4, H[(nb4.x << 4) + d]);
        s[1] = dot4(p4, H[(nb4.y << 4) + d]);
        s[2] = dot4(p4, H[(nb4.z << 4) + d]);
        s[3] = dot4(p4, H[(nb4.w << 4) + d]);
        float dap = dot4(a4, p4);

        // reduce-scatter the 4 values across the 16-lane group
        {
            bool hi = (d & 8) != 0;
            float send0 = hi ? s[0] : s[2];
            float send1 = hi ? s[1] : s[3];
            float r0 = __shfl_xor(send0, 8, 64);
            float r1 = __shfl_xor(send1, 8, 64);
            float k0 = hi ? s[2] : s[0];
            float k1 = hi ? s[3] : s[1];
            s[0] = k0 + r0;
            s[1] = k1 + r1;
        }
        float sv;
        {
            bool hi = (d & 4) != 0;
            float send = hi ? s[0] : s[1];
            float r = __shfl_xor(send, 4, 64);
            float k = hi ? s[1] : s[0];
            sv = k + r;
        }
        sv += __shfl_xor(sv, 2, 64);
        sv += __shfl_xor(sv, 1, 64);
        // lane (e,d) holds <p,n_j> for j = 4e + b, b = ((d>>3)&1)*2 + ((d>>2)&1)
        int b_lane = ((d >> 3) & 1) * 2 + ((d >> 2) & 1);
        int nidx_lane = (d & 8) ? ((d & 4) ? nb4.w : nb4.z)
                                : ((d & 4) ? nb4.y : nb4.x);
        int j_lane = 4 * e + b_lane;

        float np2 = nrm2[ip];
        float bd = nrm2[nidx_lane] + np2 - 2.0f * sv;
        int bj = j_lane;
        // wave-wide argmin, first-occurrence tie-break
        #pragma unroll
        for (int off = 32; off > 0; off >>= 1) {
            float od = __shfl_xor(bd, off, 64);
            int   oj = __shfl_xor(bj, off, 64);
            if (od < bd || (od == bd && oj < bj)) { bd = od; bj = oj; }
        }
        int bn = neg[(size_t)i * NUM_NEG + __builtin_amdgcn_readfirstlane(bj)];  // s_load
        f4 w4 = H[(bn << 4) + d];
        float dan = group_reduce16(dot4(a4, w4));
        dap = group_reduce16(dap);
        float a0 = __shfl(a4.x, 0, 64);            // same bits lane 0 used before
        float p0 = __shfl(p4.x, 0, 64);
        float n0 = __shfl(w4.x, 0, 64);

        bool sel = (lane == t);
        fdap = sel ? dap : fdap;
        fdan = sel ? dan : fdan;
        fa0  = sel ? a0  : fa0;
        fp0  = sel ? p0  : fp0;
        fn0  = sel ? n0  : fn0;
    }

    // batched finalization: lane t computes edge t's loss (t < EPW); other
    // lanes compute on benign init values (never read).
    float mink = fdap - 2.0f * fa0 * fp0;
    float th = fmaxf(-mink, 1.0f + EPS);
    float ac = acoshf(th);
    float pos_score = fminf(ac * ac, MAX_SQDIST);
    float score = (1.0f - mink - fa0 - fp0) / (fa0 * fp0);
    float wgt = 1.0f / (1.0f + expf(score));            // sigmoid(-score)
    float minkn = fdan - 2.0f * fa0 * fn0;
    float thn = fmaxf(-minkn, 1.0f + EPS);
    float acn = acoshf(thn);
    float neg_score = fminf(acn * acn, MAX_SQDIST);
    float loss = fmaxf(pos_score - neg_score + MARGIN * wgt, 0.0f);

    // strict-order 4-edge partials, same granularity/order as the old kernel
    float pa = ((__shfl(loss, 0, 64) + __shfl(loss, 1, 64)) + __shfl(loss, 2, 64)) + __shfl(loss, 3, 64);
    float pb = ((__shfl(loss, 4, 64) + __shfl(loss, 5, 64)) + __shfl(loss, 6, 64)) + __shfl(loss, 7, 64);
    if (lane == 0) {
        partials[2 * w]     = pa;
        partials[2 * w + 1] = pb;
    }
}

// Final reduce. Single block, 1024 threads. (NPART unchanged = 16384.)
__global__ void reduce_kernel(const float* __restrict__ partials, float* __restrict__ out) {
    int tid = threadIdx.x;
    float s = 0.0f;
    for (int i = tid; i < NPART; i += 1024)
        s += partials[i];
    #pragma unroll
    for (int off = 32; off > 0; off >>= 1)
        s += __shfl_xor(s, off, 64);
    __shared__ float part[16];
    if ((tid & 63) == 0) part[tid >> 6] = s;
    __syncthreads();
    if (tid == 0) {
        float t = 0.0f;
        #pragma unroll
        for (int k = 0; k < 16; ++k) t += part[k];
        out[0] = t;
    }
}

extern "C" void kernel_launch(void* const* d_in, const int* in_sizes, int n_in,
                              void* d_out, int out_size, void* d_ws, size_t ws_size,
                              hipStream_t stream) {
    const float* weight   = (const float*)d_in[0];
    const float* adj_vals = (const float*)d_in[1];
    const int*   adj_row  = (const int*)d_in[2];
    const int*   adj_col  = (const int*)d_in[3];
    const int*   anchor   = (const int*)d_in[4];
    const int*   pos      = (const int*)d_in[5];
    const int*   neg      = (const int*)d_in[6];
    float* out = (float*)d_out;

    const size_t NODEF32 = (size_t)N_NODES * EMB_DIM * sizeof(float);           // 51.2 MB
    const size_t NODEBF  = (size_t)N_NODES * EMB_DIM * sizeof(unsigned short);  // 25.6 MB
    const size_t MB = 1024 * 1024;
    char* ws = (char*)d_ws;
    float* hfin = (float*)(ws);                        // final h (fp32)
    uint2* bf0  = (uint2*)(ws + NODEF32);              // x_t bf16
    char*  bf1  = (char*) (ws + NODEF32 + NODEBF);     // h1 bf16
    char*  bf2  = (char*) (ws + NODEF32 + 2 * NODEBF); // h2 bf16
    int*   rp   = (int*)  (ws + NODEF32 + 3 * NODEBF);            // row_ptr (800 KB)
    float* nrm2 = (float*)(ws + NODEF32 + 3 * NODEBF + 1 * MB);   // ||h||^2 (800 KB)
    int2*  ev   = (int2*) (ws + NODEF32 + 3 * NODEBF + 2 * MB);   // packed edges (12.8 MB)
    float* partials = (float*)(ws + NODEF32 + 3 * NODEBF + 16 * MB); // 64 KB

    prelude_kernel<<<PACK_BLOCKS + RP_BLOCKS + LOG_BLOCKS, 256, 0, stream>>>(
        adj_col, adj_vals, ev, adj_row, rp, weight, bf0);
    spmm_kernel<<<SPMM_BLOCKS, 256, 0, stream>>>((const uint4*)bf0, (uint4*)bf1, ev, rp);
    spmm_kernel<<<SPMM_BLOCKS, 256, 0, stream>>>((const uint4*)bf1, (uint4*)bf2, ev, rp);
    spmm_expmap_kernel<<<SPMM_BLOCKS, 256, 0, stream>>>((const uint4*)bf2, (const uint4*)bf1,
                                                        (const uint4*)bf2, hfin, nrm2, ev, rp);
    loss_kernel<<<LOSS_BLOCKS, 256, 0, stream>>>(hfin, nrm2, anchor, pos, neg, partials);
    reduce_kernel<<<1, 1024, 0, stream>>>(partials, out);
}